// Round 5
// baseline (484.778 us; speedup 1.0000x reference)
//
#include <hip/hip_runtime.h>

// 9x9 local-max peak detection (threshold 0.5) on 8192x8192 fp32.
//
// conf[r][c] = (M > 0.5 && M == raw[r][c]) ? M : 0, where M = 9x9 raw max
// (threshold commutes with max; 0-pad == -inf pad given the >0.5 gate).
//
// R5: TLP-first streaming. 32-row strips -> 2048 blocks = 8192 waves
// (2x R4's 4096; machine capacity 8192). Wave = 256-col band (lane = 4
// cols), fully-unrolled 40-step roll (8 prologue + 32 emit steps) so every
// ring index is compile-time static:
//   hm[9]  : horizontal 9-max ring (36 VGPR)
//   ce[4]  : center-value delay line (16 VGPR; emit row = load from 4 steps
//            ago, and 40 % 4 == 0 keeps slots static)
// Boundary handling is clamp-duplication (dup values stay inside the true
// window; max is idempotent) -> zero boundary selects.
// __launch_bounds__(256,6) caps VGPR at ~85 -> ~24 waves/CU.

#define W 8192
#define H 8192
#define THRESH 0.5f

typedef float v4f __attribute__((ext_vector_type(4)));

__global__ __launch_bounds__(256, 6) void peak_stream(const float* __restrict__ in,
                                                      float* __restrict__ out) {
    const int lane  = threadIdx.x;                          // 0..63
    const int col0  = blockIdx.x * 256 + lane * 4;          // lane's 4 output cols
    const int strip = blockIdx.y * 4 + threadIdx.y;         // 0..255
    const int r0    = strip * 32;                           // first output row

    // Clamp-duplication halo columns (edge lanes re-read in-window values).
    const int clc = max(col0 - 4, 0);
    const int crc = min(col0 + 4, W - 4);

    v4f hm[9];   // horizontal-max ring, slot = t % 9 (static: loop fully unrolled)
    v4f ce[4];   // raw-center delay line, slot = t % 4 (static)

#pragma unroll
    for (int t = 0; t < 40; ++t) {
        const int rin = r0 - 4 + t;
        const int rc  = min(max(rin, 0), H - 1);            // row clamp-duplication
        const float* rowp = in + (size_t)rc * W;
        const v4f l = *(const v4f*)(rowp + clc);
        const v4f v = *(const v4f*)(rowp + col0);
        const v4f r = *(const v4f*)(rowp + crc);

        // L = [l0..l3 v0..v3 r0..r3] = cols col0-4 .. col0+7; o_j = max L[j..j+8]
        const float common = fmaxf(fmaxf(fmaxf(l.w, v.x), fmaxf(v.y, v.z)),
                                   fmaxf(v.w, r.x));        // max L[3..8]
        const float m12  = fmaxf(l.y, l.z);
        const float m910 = fmaxf(r.y, r.z);
        v4f o;
        o.x = fmaxf(common, fmaxf(l.x, m12));
        o.y = fmaxf(common, fmaxf(m12, r.y));
        o.z = fmaxf(common, fmaxf(l.z, m910));
        o.w = fmaxf(common, fmaxf(m910, r.w));
        hm[t % 9] = o;

        const v4f cold = ce[t % 4];   // raw center of row rin-4 (loaded 4 steps ago)
        ce[t % 4] = v;

        if (t >= 8) {
            v4f m = hm[0];
#pragma unroll
            for (int j = 1; j < 9; ++j) {
                m.x = fmaxf(m.x, hm[j].x);
                m.y = fmaxf(m.y, hm[j].y);
                m.z = fmaxf(m.z, hm[j].z);
                m.w = fmaxf(m.w, hm[j].w);
            }
            v4f ov;
            ov.x = (m.x > THRESH && m.x == cold.x) ? m.x : 0.f;
            ov.y = (m.y > THRESH && m.y == cold.y) ? m.y : 0.f;
            ov.z = (m.z > THRESH && m.z == cold.z) ? m.z : 0.f;
            ov.w = (m.w > THRESH && m.w == cold.w) ? m.w : 0.f;
            const int rout = rin - 4;                       // r0 .. r0+31
            *(v4f*)(out + (size_t)rout * W + col0) = ov;
        }
    }
}

extern "C" void kernel_launch(void* const* d_in, const int* in_sizes, int n_in,
                              void* d_out, int out_size, void* d_ws, size_t ws_size,
                              hipStream_t stream) {
    const float* in = (const float*)d_in[0];
    float* out = (float*)d_out;
    dim3 grid(W / 256, H / 128);   // 32 x 64 = 2048 blocks (block = 4 strips)
    dim3 block(64, 4, 1);          // wave ty owns strip 4*by+ty (32 rows)
    peak_stream<<<grid, block, 0, stream>>>(in, out);
}